// Round 1
// baseline (223.219 us; speedup 1.0000x reference)
//
#include <hip/hip_runtime.h>

typedef unsigned short u16;
typedef unsigned int u32;
typedef __attribute__((ext_vector_type(4))) float f32x4;
typedef __attribute__((ext_vector_type(8))) short s16x8;
typedef __attribute__((ext_vector_type(4))) int i32x4;
typedef __attribute__((ext_vector_type(2))) u32 u32x2;
typedef __attribute__((ext_vector_type(4))) u32 u32x4;

#define TT 4096
#define NEG_BIG (-3.0e38f)

__device__ __forceinline__ u16 f2bf(float x){
  u32 u = __builtin_bit_cast(u32, x);
  u32 r = (u + 0x7FFFu + ((u >> 16) & 1u)) >> 16;  // RNE
  return (u16)r;
}
__device__ __forceinline__ u32 pk2(float a, float b){
  return (u32)f2bf(a) | ((u32)f2bf(b) << 16);
}
__device__ __forceinline__ f32x4 mfma16(s16x8 a, s16x8 b, f32x4 c){
  return __builtin_amdgcn_mfma_f32_16x16x32_bf16(a, b, c, 0, 0, 0);
}

// ---------------- kernel 0: W fp32 -> bf16, Wq pre-scaled by 1/8 ----------
__global__ __launch_bounds__(256) void wconv_k(const float* __restrict__ Wq,
                                               const float* __restrict__ Wk,
                                               const float* __restrict__ Wv,
                                               u16* __restrict__ Wb){
  int i = blockIdx.x * 256 + threadIdx.x;          // 196608 = 768*256 exactly
  float v;
  if (i < 65536)       v = Wq[i] * 0.125f;         // fold 1/sqrt(64) into Q
  else if (i < 131072) v = Wk[i - 65536];
  else                 v = Wv[i - 131072];
  Wb[i] = f2bf(v);
}

// ---------------- kernel 1: QKV projection (MFMA bf16) --------------------
// X[16384][1024] fp32 -> Qb,Kb [n][64] bf16 (Q pre-scaled), Vt [b][64][4096] bf16
// Q/K: swapped mfma (D = W * X^T) -> contiguous 8B stores, Q/K row-major.
// V: normal mfma (D = X * Wv^T) -> stores land transposed into Vt[h][t].
__global__ __launch_bounds__(256) void qkv_k(const float* __restrict__ X,
                                             const u16* __restrict__ Wb,
                                             u16* __restrict__ Qb,
                                             u16* __restrict__ Kb,
                                             u16* __restrict__ Vt){
  __shared__ u16 Xs[64][40];                        // 32 data + 8 pad (80B pitch)
  const int tid = threadIdx.x;
  const int lane = tid & 63;
  const int wid = tid >> 6;
  const int q4 = lane & 15, g = lane >> 4;
  const int row0 = blockIdx.x * 64;                 // 256 blocks, never straddles batch
  const int b = row0 >> 12;
  const int trow = row0 & 4095;
  const int srow = tid >> 2, spart = tid & 3;       // staging: 4 thr/row, 8 floats each
  const float* xsrc = X + (size_t)(row0 + srow) * 1024 + spart * 8;
  f32x4 c0 = *(const f32x4*)(xsrc);
  f32x4 c1 = *(const f32x4*)(xsrc + 4);
  f32x4 acc[3][4];
  #pragma unroll
  for (int ci = 0; ci < 3; ++ci)
    #pragma unroll
    for (int tt = 0; tt < 4; ++tt) acc[ci][tt] = (f32x4){0.f, 0.f, 0.f, 0.f};
  const int ct0 = wid * 3;                          // wave handles col-tiles ct0..ct0+2

  for (int kc = 0; kc < 32; ++kc){
    s16x8 wf[3];                                    // W frags direct from L2
    #pragma unroll
    for (int ci = 0; ci < 3; ++ci){
      int ct = ct0 + ci;
      wf[ci] = *(const s16x8*)(Wb + (size_t)(ct * 16 + q4) * 1024 + kc * 32 + g * 8);
    }
    const float* nx = xsrc + (kc < 31 ? (kc + 1) * 32 : 0);  // prefetch (clamped)
    f32x4 n0 = *(const f32x4*)(nx);
    f32x4 n1 = *(const f32x4*)(nx + 4);
    u32x4 wv;
    wv[0] = pk2(c0[0], c0[1]); wv[1] = pk2(c0[2], c0[3]);
    wv[2] = pk2(c1[0], c1[1]); wv[3] = pk2(c1[2], c1[3]);
    *(u32x4*)&Xs[srow][spart * 8] = wv;             // ds_write_b128
    __syncthreads();
    s16x8 xf[4];
    #pragma unroll
    for (int tt = 0; tt < 4; ++tt) xf[tt] = *(const s16x8*)&Xs[tt * 16 + q4][g * 8];
    #pragma unroll
    for (int ci = 0; ci < 3; ++ci){
      #pragma unroll
      for (int tt = 0; tt < 4; ++tt){
        if (ct0 + ci < 8) acc[ci][tt] = mfma16(wf[ci], xf[tt], acc[ci][tt]); // Q,K: W*X^T
        else              acc[ci][tt] = mfma16(xf[tt], wf[ci], acc[ci][tt]); // V:  X*Wv^T
      }
    }
    __syncthreads();
    c0 = n0; c1 = n1;
  }
  // epilogue: C layout col=lane&15 row=4*(lane>>4)+reg -> 4 consecutive -> 8B stores
  #pragma unroll
  for (int ci = 0; ci < 3; ++ci){
    int ct = ct0 + ci;
    #pragma unroll
    for (int tt = 0; tt < 4; ++tt){
      f32x4 v = acc[ci][tt];
      u32x2 pw; pw[0] = pk2(v[0], v[1]); pw[1] = pk2(v[2], v[3]);
      if (ct < 8){   // D[h][t]: col=t fixed, rows h consecutive
        u16* dst = (ct < 4 ? Qb : Kb) + (size_t)(row0 + tt * 16 + q4) * 64 + (ct & 3) * 16 + g * 4;
        *(u32x2*)dst = pw;
      } else {       // D[t][h]: col=h fixed, rows t consecutive -> Vt[b][h][t]
        u16* dst = Vt + (size_t)(b * 64 + (ct - 8) * 16 + q4) * TT + trow + tt * 16 + g * 4;
        *(u32x2*)dst = pw;
      }
    }
  }
}

// ---------------- kernel 2: causal flash attention ------------------------
// Block = 2 waves, handles strip pair (p, 255-p) of batch b with 2-way k-split.
// Swapped QK^T: S^T = mfma(Kfrag, Qfrag) -> lane owns one query column.
__global__ __launch_bounds__(128) void attn_k(const u16* __restrict__ Qb,
                                              const u16* __restrict__ Kb,
                                              const u16* __restrict__ Vt,
                                              const int* __restrict__ km,
                                              float* __restrict__ out){
  __shared__ u16 Plds[2][16][72];      // per-wave P buffer [q][key], pitch 144B
  __shared__ float Part[2][16][64];    // partner partials per strip-slot
  __shared__ float Pml[2][2][16];      // m,l partials
  const int tid = threadIdx.x;
  const int wid = tid >> 6;
  const int lane = tid & 63;
  const int q4 = lane & 15, g = lane >> 4;
  const int b = blockIdx.x >> 7;
  const int p = blockIdx.x & 127;
  float mK, lK; f32x4 oK[4];

  #pragma unroll
  for (int si = 0; si < 2; ++si){
    const int s = (si == 0) ? p : 255 - p;
    const int qbase = s * 16;
    const int q_lane = qbase + q4;
    const int ntiles = (s >> 2) + 1;               // KBLK=64 tiles covering keys<=qmax
    const int t0 = (ntiles * wid) >> 1;            // 2-way k-split across waves
    const int t1 = (ntiles * (wid + 1)) >> 1;
    const u16* qptr = Qb + (size_t)(b * TT + qbase + q4) * 64 + g * 8;
    const s16x8 qf0 = *(const s16x8*)(qptr);       // Q pre-scaled by 1/8
    const s16x8 qf1 = *(const s16x8*)(qptr + 32);
    float m = NEG_BIG, l = 0.f;
    f32x4 o[4];
    #pragma unroll
    for (int ht = 0; ht < 4; ++ht) o[ht] = (f32x4){0.f, 0.f, 0.f, 0.f};

    for (int kt = t0; kt < t1; ++kt){
      const int kb = kt * 64;
      const u16* kp = Kb + (size_t)(b * TT + kb + q4) * 64 + g * 8;
      s16x8 kf[4][2];
      #pragma unroll
      for (int mt = 0; mt < 4; ++mt){
        kf[mt][0] = *(const s16x8*)(kp + mt * 1024);
        kf[mt][1] = *(const s16x8*)(kp + mt * 1024 + 32);
      }
      f32x4 sA[4];
      #pragma unroll
      for (int mt = 0; mt < 4; ++mt){
        sA[mt] = mfma16(kf[mt][0], qf0, (f32x4){0.f, 0.f, 0.f, 0.f});
        sA[mt] = mfma16(kf[mt][1], qf1, sA[mt]);
      }
      // padding mask (semantics; all-ones in test)
      #pragma unroll
      for (int mt = 0; mt < 4; ++mt){
        i32x4 mk = *(const i32x4*)(km + b * TT + kb + mt * 16 + g * 4);
        #pragma unroll
        for (int r = 0; r < 4; ++r) if (mk[r] == 0) sA[mt][r] = NEG_BIG;
      }
      // causal mask only ever needed on the last tile of the strip
      if (kt == ntiles - 1){
        #pragma unroll
        for (int mt = 0; mt < 4; ++mt)
          #pragma unroll
          for (int r = 0; r < 4; ++r){
            int key = kb + mt * 16 + g * 4 + r;
            if (key > q_lane) sA[mt][r] = NEG_BIG;
          }
      }
      // online softmax: lane owns query q4; keys spread over 4-lane group
      float vmax = NEG_BIG;
      #pragma unroll
      for (int mt = 0; mt < 4; ++mt)
        #pragma unroll
        for (int r = 0; r < 4; ++r) vmax = fmaxf(vmax, sA[mt][r]);
      vmax = fmaxf(vmax, __shfl_xor(vmax, 16));
      vmax = fmaxf(vmax, __shfl_xor(vmax, 32));
      const float mn = fmaxf(m, vmax);
      const float sc = __expf(m - mn);
      float ps = 0.f;
      float pvv[4][4];
      #pragma unroll
      for (int mt = 0; mt < 4; ++mt)
        #pragma unroll
        for (int r = 0; r < 4; ++r){
          float e = __expf(sA[mt][r] - mn);
          pvv[mt][r] = e; ps += e;
        }
      ps += __shfl_xor(ps, 16);
      ps += __shfl_xor(ps, 32);
      l = l * sc + ps;
      m = mn;
      #pragma unroll
      for (int ht = 0; ht < 4; ++ht) o[ht] *= sc;
      // P -> bf16 via per-wave LDS [q][key] (wave-local, no barrier)
      #pragma unroll
      for (int mt = 0; mt < 4; ++mt){
        u32x2 pw; pw[0] = pk2(pvv[mt][0], pvv[mt][1]); pw[1] = pk2(pvv[mt][2], pvv[mt][3]);
        *(u32x2*)&Plds[wid][q4][mt * 16 + g * 4] = pw;
      }
      const s16x8 pf0 = *(const s16x8*)&Plds[wid][q4][g * 8];
      const s16x8 pf1 = *(const s16x8*)&Plds[wid][q4][32 + g * 8];
      const u16* vp = Vt + (size_t)(b * 64 + q4) * TT + kb + g * 8;
      #pragma unroll
      for (int ht = 0; ht < 4; ++ht){
        s16x8 vf0 = *(const s16x8*)(vp + (size_t)(ht * 16) * TT);
        s16x8 vf1 = *(const s16x8*)(vp + (size_t)(ht * 16) * TT + 32);
        o[ht] = mfma16(vf0, pf0, o[ht]);   // O^T[h][q] += V^T * P^T
        o[ht] = mfma16(vf1, pf1, o[ht]);
      }
    }
    if (si != wid){   // hand partial to partner wave via LDS
      #pragma unroll
      for (int ht = 0; ht < 4; ++ht) *(f32x4*)&Part[si][q4][ht * 16 + g * 4] = o[ht];
      if (g == 0){ Pml[si][0][q4] = m; Pml[si][1][q4] = l; }
    } else {          // keep own merge-strip partial in named regs (no dyn idx)
      mK = m; lK = l;
      #pragma unroll
      for (int ht = 0; ht < 4; ++ht) oK[ht] = o[ht];
    }
  }
  __syncthreads();
  // merge: wave wid finalizes strip (wid==0 ? p : 255-p)
  const int s = (wid == 0) ? p : 255 - p;
  const float m1 = Pml[wid][0][q4], l1 = Pml[wid][1][q4];
  const float mt_ = fmaxf(mK, m1);
  const float a = __expf(mK - mt_), bb = __expf(m1 - mt_);
  const float lt = lK * a + l1 * bb;
  const float rl = 1.0f / lt;
  float* op = out + (size_t)(b * TT + s * 16 + q4) * 64;
  #pragma unroll
  for (int ht = 0; ht < 4; ++ht){
    f32x4 o1 = *(const f32x4*)&Part[wid][q4][ht * 16 + g * 4];
    f32x4 ov;
    #pragma unroll
    for (int r = 0; r < 4; ++r) ov[r] = (oK[ht][r] * a + o1[r] * bb) * rl;
    *(f32x4*)(op + ht * 16 + g * 4) = ov;
  }
}

extern "C" void kernel_launch(void* const* d_in, const int* in_sizes, int n_in,
                              void* d_out, int out_size, void* d_ws, size_t ws_size,
                              hipStream_t stream){
  const float* X  = (const float*)d_in[0];
  const float* Wq = (const float*)d_in[1];
  const float* Wk = (const float*)d_in[2];
  const float* Wv = (const float*)d_in[3];
  const int*   km = (const int*)d_in[4];
  float* out = (float*)d_out;
  u16* Qb = (u16*)d_ws;                 // [16384][64] bf16, pre-scaled by 1/8
  u16* Kb = Qb + (size_t)16384 * 64;    // [16384][64] bf16
  u16* Vt = Kb + (size_t)16384 * 64;    // [4][64][4096] bf16 (transposed V)
  u16* Wb = Vt + (size_t)16384 * 64;    // [192][1024] bf16 (Wq|Wk|Wv)
  hipLaunchKernelGGL(wconv_k, dim3(768), dim3(256), 0, stream, Wq, Wk, Wv, Wb);
  hipLaunchKernelGGL(qkv_k,   dim3(256), dim3(256), 0, stream, X, Wb, Qb, Kb, Vt);
  hipLaunchKernelGGL(attn_k,  dim3(512), dim3(128), 0, stream, Qb, Kb, Vt, km, out);
}

// Round 4
// 192.484 us; speedup vs baseline: 1.1597x; 1.1597x over previous
//
#include <hip/hip_runtime.h>

typedef unsigned short u16;
typedef unsigned int u32;
typedef __attribute__((ext_vector_type(4))) float f32x4;
typedef __attribute__((ext_vector_type(8))) short s16x8;
typedef __attribute__((ext_vector_type(4))) int i32x4;
typedef __attribute__((ext_vector_type(2))) u32 u32x2;

#define TT 4096
#define NEG_BIG (-3.0e38f)

__device__ __forceinline__ u16 f2bf(float x){
  u32 u = __builtin_bit_cast(u32, x);
  u32 r = (u + 0x7FFFu + ((u >> 16) & 1u)) >> 16;  // RNE
  return (u16)r;
}
__device__ __forceinline__ u32 pk2(float a, float b){
  return (u32)f2bf(a) | ((u32)f2bf(b) << 16);
}
__device__ __forceinline__ f32x4 mfma16(s16x8 a, s16x8 b, f32x4 c){
  return __builtin_amdgcn_mfma_f32_16x16x32_bf16(a, b, c, 0, 0, 0);
}

// ---------------- kernel 0: W fp32 -> bf16, Wq pre-scaled by 1/8 ----------
__global__ __launch_bounds__(256) void wconv_k(const float* __restrict__ Wq,
                                               const float* __restrict__ Wk,
                                               const float* __restrict__ Wv,
                                               u16* __restrict__ Wb){
  int i = blockIdx.x * 256 + threadIdx.x;          // 196608 = 768*256 exactly
  float v;
  if (i < 65536)       v = Wq[i] * 0.125f;         // fold 1/sqrt(64) into Q
  else if (i < 131072) v = Wk[i - 65536];
  else                 v = Wv[i - 131072];
  Wb[i] = f2bf(v);
}

// ---------------- kernel 1: QKV projection (MFMA bf16) --------------------
// 512 blocks x 32 rows (2 blocks/CU so barrier drains overlap across blocks).
// Q/K: swapped mfma (D = W * X^T) -> contiguous 8B stores, Q/K row-major.
// V: normal mfma (D = X * Wv^T) -> stores land transposed into Vt[b][h][t].
__global__ __launch_bounds__(256) void qkv_k(const float* __restrict__ X,
                                             const u16* __restrict__ Wb,
                                             u16* __restrict__ Qb,
                                             u16* __restrict__ Kb,
                                             u16* __restrict__ Vt){
  __shared__ u16 Xs[32][40];                        // 32 data + 8 pad (80B pitch)
  const int tid = threadIdx.x;
  const int lane = tid & 63;
  const int wid = tid >> 6;
  const int q4 = lane & 15, g = lane >> 4;
  const int row0 = blockIdx.x * 32;                 // 512 blocks, never straddles batch
  const int b = row0 >> 12;
  const int trow = row0 & 4095;
  const int srow = tid >> 3, spart = tid & 7;       // staging: 8 thr/row, 4 floats each
  const float* xsrc = X + (size_t)(row0 + srow) * 1024 + spart * 4;
  f32x4 c0 = *(const f32x4*)(xsrc);
  f32x4 acc[3][2];
  #pragma unroll
  for (int ci = 0; ci < 3; ++ci)
    #pragma unroll
    for (int tt = 0; tt < 2; ++tt) acc[ci][tt] = (f32x4){0.f, 0.f, 0.f, 0.f};
  const int ct0 = wid * 3;                          // wave handles col-tiles ct0..ct0+2

  for (int kc = 0; kc < 32; ++kc){
    s16x8 wf[3];                                    // W frags direct from L2
    #pragma unroll
    for (int ci = 0; ci < 3; ++ci){
      int ct = ct0 + ci;
      wf[ci] = *(const s16x8*)(Wb + (size_t)(ct * 16 + q4) * 1024 + kc * 32 + g * 8);
    }
    const float* nx = xsrc + (kc < 31 ? (kc + 1) * 32 : 0);  // prefetch (clamped)
    f32x4 n0 = *(const f32x4*)(nx);
    u32x2 wv;
    wv[0] = pk2(c0[0], c0[1]); wv[1] = pk2(c0[2], c0[3]);
    *(u32x2*)&Xs[srow][spart * 4] = wv;             // ds_write_b64
    __syncthreads();
    s16x8 xf[2];
    #pragma unroll
    for (int tt = 0; tt < 2; ++tt) xf[tt] = *(const s16x8*)&Xs[tt * 16 + q4][g * 8];
    #pragma unroll
    for (int ci = 0; ci < 3; ++ci){
      #pragma unroll
      for (int tt = 0; tt < 2; ++tt){
        if (ct0 + ci < 8) acc[ci][tt] = mfma16(wf[ci], xf[tt], acc[ci][tt]); // Q,K: W*X^T
        else              acc[ci][tt] = mfma16(xf[tt], wf[ci], acc[ci][tt]); // V:  X*Wv^T
      }
    }
    __syncthreads();
    c0 = n0;
  }
  // epilogue: C layout col=lane&15 row=4*(lane>>4)+reg -> 4 consecutive -> 8B stores
  #pragma unroll
  for (int ci = 0; ci < 3; ++ci){
    int ct = ct0 + ci;
    #pragma unroll
    for (int tt = 0; tt < 2; ++tt){
      f32x4 v = acc[ci][tt];
      u32x2 pw; pw[0] = pk2(v[0], v[1]); pw[1] = pk2(v[2], v[3]);
      if (ct < 8){   // D[h][t]: col=t fixed, rows h consecutive
        u16* dst = (ct < 4 ? Qb : Kb) + (size_t)(row0 + tt * 16 + q4) * 64 + (ct & 3) * 16 + g * 4;
        *(u32x2*)dst = pw;
      } else {       // D[t][h]: col=h fixed, rows t consecutive -> Vt[b][h][t]
        u16* dst = Vt + (size_t)(b * 64 + (ct - 8) * 16 + q4) * TT + trow + tt * 16 + g * 4;
        *(u32x2*)dst = pw;
      }
    }
  }
}

// ---------------- kernel 2: causal flash attention ------------------------
// Block = 8 waves (512 thr): strip pair (p, 255-p), 4-way k-split per strip.
// 512 blocks x 8 waves = 4096 waves (4/SIMD) for latency hiding.
// Swapped QK^T: S^T = mfma(Kfrag, Qfrag) -> lane owns one query column.
__global__ __launch_bounds__(512, 4) void attn_k(const u16* __restrict__ Qb,
                                                 const u16* __restrict__ Kb,
                                                 const u16* __restrict__ Vt,
                                                 const int* __restrict__ km,
                                                 float* __restrict__ out){
  __shared__ u16 Plds[8][16][72];      // per-wave P buffer [q][key], pitch 144B
  __shared__ float Part[2][4][16][68]; // o partials [strip][quarter][q][h], padded
  __shared__ float Pml[2][4][2][16];   // m,l partials
  const int tid = threadIdx.x;
  const int wid = tid >> 6;
  const int lane = tid & 63;
  const int q4 = lane & 15, g = lane >> 4;
  const int b = blockIdx.x >> 7;
  const int p = blockIdx.x & 127;
  const int si = wid & 1;              // which strip of the pair
  const int qt = wid >> 1;             // which k-quarter

  const int s = (si == 0) ? p : 255 - p;
  const int qbase = s * 16;
  const int q_lane = qbase + q4;
  const int ntiles = (s >> 2) + 1;               // KBLK=64 tiles covering keys<=qmax
  const int t0 = (ntiles * qt) >> 2;             // 4-way k-split across quarters
  const int t1 = (ntiles * (qt + 1)) >> 2;
  const u16* qptr = Qb + (size_t)(b * TT + qbase + q4) * 64 + g * 8;
  const s16x8 qf0 = *(const s16x8*)(qptr);       // Q pre-scaled by 1/8
  const s16x8 qf1 = *(const s16x8*)(qptr + 32);
  float m = NEG_BIG, l = 0.f;
  f32x4 o[4];
  #pragma unroll
  for (int ht = 0; ht < 4; ++ht) o[ht] = (f32x4){0.f, 0.f, 0.f, 0.f};

  for (int kt = t0; kt < t1; ++kt){
    const int kb = kt * 64;
    const u16* kp = Kb + (size_t)(b * TT + kb + q4) * 64 + g * 8;
    s16x8 kf[4][2];
    #pragma unroll
    for (int mt = 0; mt < 4; ++mt){
      kf[mt][0] = *(const s16x8*)(kp + mt * 1024);
      kf[mt][1] = *(const s16x8*)(kp + mt * 1024 + 32);
    }
    f32x4 sA[4];
    #pragma unroll
    for (int mt = 0; mt < 4; ++mt){
      sA[mt] = mfma16(kf[mt][0], qf0, (f32x4){0.f, 0.f, 0.f, 0.f});
      sA[mt] = mfma16(kf[mt][1], qf1, sA[mt]);
    }
    // padding mask (semantics; all-ones in test)
    #pragma unroll
    for (int mt = 0; mt < 4; ++mt){
      i32x4 mk = *(const i32x4*)(km + b * TT + kb + mt * 16 + g * 4);
      #pragma unroll
      for (int r = 0; r < 4; ++r) if (mk[r] == 0) sA[mt][r] = NEG_BIG;
    }
    // causal mask only ever needed on the last tile of the strip
    if (kt == ntiles - 1){
      #pragma unroll
      for (int mt = 0; mt < 4; ++mt)
        #pragma unroll
        for (int r = 0; r < 4; ++r){
          int key = kb + mt * 16 + g * 4 + r;
          if (key > q_lane) sA[mt][r] = NEG_BIG;
        }
    }
    // online softmax: lane owns query q4; keys spread over 4-lane group
    float vmax = NEG_BIG;
    #pragma unroll
    for (int mt = 0; mt < 4; ++mt)
      #pragma unroll
      for (int r = 0; r < 4; ++r) vmax = fmaxf(vmax, sA[mt][r]);
    vmax = fmaxf(vmax, __shfl_xor(vmax, 16));
    vmax = fmaxf(vmax, __shfl_xor(vmax, 32));
    const float mn = fmaxf(m, vmax);
    const float sc = __expf(m - mn);
    float ps = 0.f;
    // exp + pack P -> bf16 directly into per-wave LDS (no register array)
    #pragma unroll
    for (int mt = 0; mt < 4; ++mt){
      float e0 = __expf(sA[mt][0] - mn), e1 = __expf(sA[mt][1] - mn);
      float e2 = __expf(sA[mt][2] - mn), e3 = __expf(sA[mt][3] - mn);
      ps += (e0 + e1) + (e2 + e3);
      u32x2 pw; pw[0] = pk2(e0, e1); pw[1] = pk2(e2, e3);
      *(u32x2*)&Plds[wid][q4][mt * 16 + g * 4] = pw;
    }
    ps += __shfl_xor(ps, 16);
    ps += __shfl_xor(ps, 32);
    l = l * sc + ps;
    m = mn;
    #pragma unroll
    for (int ht = 0; ht < 4; ++ht) o[ht] *= sc;
    const s16x8 pf0 = *(const s16x8*)&Plds[wid][q4][g * 8];
    const s16x8 pf1 = *(const s16x8*)&Plds[wid][q4][32 + g * 8];
    const u16* vp = Vt + (size_t)(b * 64 + q4) * TT + kb + g * 8;
    #pragma unroll
    for (int ht = 0; ht < 4; ++ht){
      s16x8 vf0 = *(const s16x8*)(vp + (size_t)(ht * 16) * TT);
      s16x8 vf1 = *(const s16x8*)(vp + (size_t)(ht * 16) * TT + 32);
      o[ht] = mfma16(vf0, pf0, o[ht]);   // O^T[h][q] += V^T * P^T
      o[ht] = mfma16(vf1, pf1, o[ht]);
    }
  }
  // publish partials
  #pragma unroll
  for (int ht = 0; ht < 4; ++ht) *(f32x4*)&Part[si][qt][q4][ht * 16 + g * 4] = o[ht];
  if (g == 0){ Pml[si][qt][0][q4] = m; Pml[si][qt][1][q4] = l; }
  __syncthreads();
  // merge: wave 0 finalizes strip p, wave 1 finalizes strip 255-p
  if (wid < 2){
    const int so = (wid == 0) ? p : 255 - p;
    float mm0 = Pml[wid][0][0][q4], mm1 = Pml[wid][1][0][q4];
    float mm2 = Pml[wid][2][0][q4], mm3 = Pml[wid][3][0][q4];
    float ll0 = Pml[wid][0][1][q4], ll1 = Pml[wid][1][1][q4];
    float ll2 = Pml[wid][2][1][q4], ll3 = Pml[wid][3][1][q4];
    const float mt_ = fmaxf(fmaxf(mm0, mm1), fmaxf(mm2, mm3));
    const float w0 = __expf(mm0 - mt_), w1 = __expf(mm1 - mt_);
    const float w2 = __expf(mm2 - mt_), w3 = __expf(mm3 - mt_);
    const float lt = ll0 * w0 + ll1 * w1 + ll2 * w2 + ll3 * w3;
    const float rl = 1.0f / lt;
    float* op = out + (size_t)(b * TT + so * 16 + q4) * 64;
    #pragma unroll
    for (int ht = 0; ht < 4; ++ht){
      f32x4 o0 = *(const f32x4*)&Part[wid][0][q4][ht * 16 + g * 4];
      f32x4 o1 = *(const f32x4*)&Part[wid][1][q4][ht * 16 + g * 4];
      f32x4 o2 = *(const f32x4*)&Part[wid][2][q4][ht * 16 + g * 4];
      f32x4 o3 = *(const f32x4*)&Part[wid][3][q4][ht * 16 + g * 4];
      f32x4 ov = (o0 * w0 + o1 * w1 + o2 * w2 + o3 * w3) * rl;
      *(f32x4*)(op + ht * 16 + g * 4) = ov;
    }
  }
}

extern "C" void kernel_launch(void* const* d_in, const int* in_sizes, int n_in,
                              void* d_out, int out_size, void* d_ws, size_t ws_size,
                              hipStream_t stream){
  const float* X  = (const float*)d_in[0];
  const float* Wq = (const float*)d_in[1];
  const float* Wk = (const float*)d_in[2];
  const float* Wv = (const float*)d_in[3];
  const int*   km = (const int*)d_in[4];
  float* out = (float*)d_out;
  u16* Qb = (u16*)d_ws;                 // [16384][64] bf16, pre-scaled by 1/8
  u16* Kb = Qb + (size_t)16384 * 64;    // [16384][64] bf16
  u16* Vt = Kb + (size_t)16384 * 64;    // [4][64][4096] bf16 (transposed V)
  u16* Wb = Vt + (size_t)16384 * 64;    // [192][1024] bf16 (Wq|Wk|Wv)
  hipLaunchKernelGGL(wconv_k, dim3(768), dim3(256), 0, stream, Wq, Wk, Wv, Wb);
  hipLaunchKernelGGL(qkv_k,   dim3(512), dim3(256), 0, stream, X, Wb, Qb, Kb, Vt);
  hipLaunchKernelGGL(attn_k,  dim3(512), dim3(512), 0, stream, Qb, Kb, Vt, km, out);
}